// Round 1
// baseline (5611.594 us; speedup 1.0000x reference)
//
#include <hip/hip_runtime.h>
#include <hip/hip_bf16.h>

// ---------------------------------------------------------------------------
// GIN multi-task forward on MI355X, fp32 baseline.
// Pipeline:
//   agg1 = scatter_add(x[src] -> dst)            (atomics)
//   h1   = relu((x+agg1) @ W1a + b1a)            (fused-add tiled SGEMM)
//   x2   = relu(h1 @ W1b + b1b)
//   agg2 = scatter_add(x2[src] -> dst)
//   h2a  = relu((x2+agg2) @ W2a + b2a)
//   h2   = relu(h2a @ W2b + b2b)
//   pooled = segment_mean(h2, batch)             (batch sorted -> binary search)
//   g = relu(pooled @ Ws + bs); 3 heads -> d_out
// ---------------------------------------------------------------------------

#define IN_DIM 128

__device__ __forceinline__ int lower_bound_i(const int* __restrict__ a, int n, int v) {
    int lo = 0, hi = n;
    while (lo < hi) {
        int mid = (lo + hi) >> 1;
        if (a[mid] < v) lo = mid + 1; else hi = mid;
    }
    return lo;
}

// ---------------------------------------------------------------------------
// scatter-add: agg[dst[e]][:] += x[src[e]][:].  32 float4 per row; 32 threads
// cooperate on one edge (consecutive lanes -> consecutive float4: coalesced).
// ---------------------------------------------------------------------------
__global__ __launch_bounds__(256) void scatter_add_kernel(
    const float4* __restrict__ x4, const int* __restrict__ src,
    const int* __restrict__ dst, float* __restrict__ agg, int n_edges)
{
    int t = blockIdx.x * 256 + threadIdx.x;
    int e = t >> 5;
    int f = t & 31;
    if (e >= n_edges) return;
    int s = src[e];
    int d = dst[e];
    float4 v = x4[(size_t)s * 32 + f];
    float* out = agg + (size_t)d * IN_DIM + f * 4;
    atomicAdd(out + 0, v.x);
    atomicAdd(out + 1, v.y);
    atomicAdd(out + 2, v.z);
    atomicAdd(out + 3, v.w);
}

// ---------------------------------------------------------------------------
// Tiled SGEMM: C[M x 128] = relu((A1 (+A2)) @ W[128 x 128] + bias), fp32.
// Block: 256 threads, tile 64 rows x 128 cols, per-thread 8x4 register tile.
// K staged in chunks of 16: As transposed (k-major, pad to 68 for 16B-aligned
// float4 rows), Ws chunk staged directly.
// ---------------------------------------------------------------------------
template <bool FUSE_ADD>
__global__ __launch_bounds__(256) void gemm128_kernel(
    const float* __restrict__ A1, const float* __restrict__ A2,
    const float* __restrict__ W, const float* __restrict__ bias,
    float* __restrict__ C, int M)
{
    __shared__ float As[16][68];    // [k][row], 68*4=272B rows keep float4 alignment
    __shared__ float Bs[16][128];   // [k][col]

    const int t  = threadIdx.x;
    const int tx = t & 31;          // col group: cols tx*4 .. tx*4+3
    const int ty = t >> 5;          // row group: rows ty*8 .. ty*8+7
    const int row0 = blockIdx.x * 64;

    float acc[8][4];
#pragma unroll
    for (int i = 0; i < 8; ++i)
#pragma unroll
        for (int j = 0; j < 4; ++j) acc[i][j] = 0.f;

    const int arow = t >> 2;        // 0..63 (A-tile row this thread stages)
    const int kq   = t & 3;         // which float4 of the 16-wide k-chunk
    const int grow = row0 + arow;
    const int kr   = t >> 5;        // 0..7 (W-tile k-rows kr and kr+8)

    for (int k0 = 0; k0 < IN_DIM; k0 += 16) {
        float4 av = make_float4(0.f, 0.f, 0.f, 0.f);
        if (grow < M) {
            av = *(const float4*)(A1 + (size_t)grow * IN_DIM + k0 + kq * 4);
            if (FUSE_ADD) {
                float4 bv = *(const float4*)(A2 + (size_t)grow * IN_DIM + k0 + kq * 4);
                av.x += bv.x; av.y += bv.y; av.z += bv.z; av.w += bv.w;
            }
        }
        float4 w0 = *(const float4*)(W + (size_t)(k0 + kr)     * IN_DIM + tx * 4);
        float4 w1 = *(const float4*)(W + (size_t)(k0 + kr + 8) * IN_DIM + tx * 4);

        As[kq * 4 + 0][arow] = av.x;
        As[kq * 4 + 1][arow] = av.y;
        As[kq * 4 + 2][arow] = av.z;
        As[kq * 4 + 3][arow] = av.w;
        *(float4*)&Bs[kr][tx * 4]     = w0;
        *(float4*)&Bs[kr + 8][tx * 4] = w1;
        __syncthreads();

#pragma unroll
        for (int kk = 0; kk < 16; ++kk) {
            float4 a0 = *(const float4*)&As[kk][ty * 8];
            float4 a1 = *(const float4*)&As[kk][ty * 8 + 4];
            float4 w  = *(const float4*)&Bs[kk][tx * 4];
            float a[8] = {a0.x, a0.y, a0.z, a0.w, a1.x, a1.y, a1.z, a1.w};
            float wv[4] = {w.x, w.y, w.z, w.w};
#pragma unroll
            for (int i = 0; i < 8; ++i)
#pragma unroll
                for (int j = 0; j < 4; ++j)
                    acc[i][j] = fmaf(a[i], wv[j], acc[i][j]);
        }
        __syncthreads();
    }

    float4 bv = *(const float4*)(bias + tx * 4);
    float b[4] = {bv.x, bv.y, bv.z, bv.w};
#pragma unroll
    for (int i = 0; i < 8; ++i) {
        int r = row0 + ty * 8 + i;
        if (r < M) {
            float4 o;
            o.x = fmaxf(acc[i][0] + b[0], 0.f);
            o.y = fmaxf(acc[i][1] + b[1], 0.f);
            o.z = fmaxf(acc[i][2] + b[2], 0.f);
            o.w = fmaxf(acc[i][3] + b[3], 0.f);
            *(float4*)(C + (size_t)r * IN_DIM + tx * 4) = o;
        }
    }
}

// ---------------------------------------------------------------------------
// Mean-pool per graph. batch is sorted -> per-graph contiguous range found by
// binary search (uniform across the block; no atomics, deterministic).
// ---------------------------------------------------------------------------
__global__ __launch_bounds__(128) void pool_kernel(
    const float* __restrict__ h, const int* __restrict__ batch,
    float* __restrict__ pooled, int n_nodes, int n_graphs)
{
    int g = blockIdx.x;
    int lo = lower_bound_i(batch, n_nodes, g);
    int hi = lower_bound_i(batch, n_nodes, g + 1);
    int j = threadIdx.x;  // 0..127
    float acc = 0.f;
    for (int i = lo; i < hi; ++i)
        acc += h[(size_t)i * IN_DIM + j];
    float cnt = (float)(hi - lo);
    pooled[(size_t)g * IN_DIM + j] = acc / fmaxf(cnt, 1.0f);
}

// ---------------------------------------------------------------------------
// Shared MLP + 3 linear heads, one wave per graph.
// g_j = relu(bs[j] + sum_k pooled[k]*Ws[k][j]); out = wave-reduced g . W_head
// ---------------------------------------------------------------------------
__global__ __launch_bounds__(64) void head_kernel(
    const float* __restrict__ pooled,
    const float* __restrict__ Ws,  const float* __restrict__ bs,
    const float* __restrict__ WlS, const float* __restrict__ blS,
    const float* __restrict__ WlP, const float* __restrict__ blP,
    const float* __restrict__ WnR, const float* __restrict__ bnR,
    float* __restrict__ out, int n_graphs)
{
    int g = blockIdx.x;
    int j = threadIdx.x;  // 0..63
    const float* p = pooled + (size_t)g * IN_DIM;
    float acc = bs[j];
#pragma unroll 8
    for (int k = 0; k < IN_DIM; ++k)
        acc = fmaf(p[k], Ws[k * 64 + j], acc);
    float gj = fmaxf(acc, 0.f);
    float s1 = gj * WlS[j];
    float s2 = gj * WlP[j];
    float s3 = gj * WnR[j];
#pragma unroll
    for (int off = 32; off > 0; off >>= 1) {
        s1 += __shfl_down(s1, off);
        s2 += __shfl_down(s2, off);
        s3 += __shfl_down(s3, off);
    }
    if (j == 0) {
        out[g]                = s1 + blS[0];
        out[n_graphs + g]     = s2 + blP[0];
        out[2 * n_graphs + g] = s3 + bnR[0];
    }
}

extern "C" void kernel_launch(void* const* d_in, const int* in_sizes, int n_in,
                              void* d_out, int out_size, void* d_ws, size_t ws_size,
                              hipStream_t stream)
{
    const float* x   = (const float*)d_in[0];
    const int*   ei  = (const int*)d_in[1];
    const int*   bat = (const int*)d_in[2];
    const float* W1a = (const float*)d_in[3];
    const float* b1a = (const float*)d_in[4];
    const float* W1b = (const float*)d_in[5];
    const float* b1b = (const float*)d_in[6];
    const float* W2a = (const float*)d_in[7];
    const float* b2a = (const float*)d_in[8];
    const float* W2b = (const float*)d_in[9];
    const float* b2b = (const float*)d_in[10];
    const float* Ws  = (const float*)d_in[11];
    const float* bs  = (const float*)d_in[12];
    const float* WlS = (const float*)d_in[13];
    const float* blS = (const float*)d_in[14];
    const float* WlP = (const float*)d_in[15];
    const float* blP = (const float*)d_in[16];
    const float* WnR = (const float*)d_in[17];
    const float* bnR = (const float*)d_in[18];

    const int n_nodes  = in_sizes[0] / IN_DIM;
    const int n_edges  = in_sizes[1] / 2;
    const int n_graphs = out_size / 3;
    const int* src = ei;
    const int* dst = ei + n_edges;

    const size_t node_elems = (size_t)n_nodes * IN_DIM;
    float* agg    = (float*)d_ws;
    float* h1     = agg  + node_elems;
    float* buf2   = h1   + node_elems;
    float* pooled = buf2 + node_elems;

    const size_t node_bytes = node_elems * sizeof(float);
    const int sblocks = (int)(((size_t)n_edges * 32 + 255) / 256);
    const int gblocks = (n_nodes + 63) / 64;

    // ---- layer 1 ----
    hipMemsetAsync(agg, 0, node_bytes, stream);
    scatter_add_kernel<<<sblocks, 256, 0, stream>>>((const float4*)x, src, dst, agg, n_edges);
    gemm128_kernel<true ><<<gblocks, 256, 0, stream>>>(x,   agg,     W1a, b1a, h1,   n_nodes);
    gemm128_kernel<false><<<gblocks, 256, 0, stream>>>(h1,  nullptr, W1b, b1b, buf2, n_nodes);

    // ---- layer 2 ----
    hipMemsetAsync(agg, 0, node_bytes, stream);
    scatter_add_kernel<<<sblocks, 256, 0, stream>>>((const float4*)buf2, src, dst, agg, n_edges);
    gemm128_kernel<true ><<<gblocks, 256, 0, stream>>>(buf2, agg,     W2a, b2a, h1,   n_nodes);
    gemm128_kernel<false><<<gblocks, 256, 0, stream>>>(h1,  nullptr,  W2b, b2b, buf2, n_nodes);

    // ---- pool + heads ----
    pool_kernel<<<n_graphs, 128, 0, stream>>>(buf2, bat, pooled, n_nodes, n_graphs);
    head_kernel<<<n_graphs, 64, 0, stream>>>(pooled, Ws, bs, WlS, blS, WlP, blP,
                                             WnR, bnR, (float*)d_out, n_graphs);
}

// Round 2
// 668.581 us; speedup vs baseline: 8.3933x; 8.3933x over previous
//
#include <hip/hip_runtime.h>
#include <hip/hip_bf16.h>

// ---------------------------------------------------------------------------
// GIN multi-task forward on MI355X.
// R2: replace fp32 atomic scatter-add (3.2 GB write-through per layer, 2.7 ms)
// with per-call CSR build + register-accumulating gather (one 32-lane group
// per destination node). The GIN "x + agg" add is fused into the gather.
// ---------------------------------------------------------------------------

#define IN_DIM 128

// ---------------- CSR build ------------------------------------------------

__global__ __launch_bounds__(256) void hist_kernel(
    const int* __restrict__ dst, int* __restrict__ counts, int n_edges)
{
    int e = blockIdx.x * 256 + threadIdx.x;
    if (e < n_edges) atomicAdd(&counts[dst[e]], 1);
}

// phase A: per-block (256 elems) totals
__global__ __launch_bounds__(256) void scan_phaseA(
    const int* __restrict__ counts, int* __restrict__ block_sums, int n)
{
    __shared__ int s[256];
    int i = blockIdx.x * 256 + threadIdx.x;
    s[threadIdx.x] = (i < n) ? counts[i] : 0;
    __syncthreads();
    for (int off = 128; off > 0; off >>= 1) {
        if (threadIdx.x < off) s[threadIdx.x] += s[threadIdx.x + off];
        __syncthreads();
    }
    if (threadIdx.x == 0) block_sums[blockIdx.x] = s[0];
}

// phase B: single-block exclusive scan of block sums (nb <= 256)
__global__ __launch_bounds__(256) void scan_phaseB(int* __restrict__ block_sums, int nb)
{
    __shared__ int s[256];
    int v = (threadIdx.x < nb) ? block_sums[threadIdx.x] : 0;
    s[threadIdx.x] = v;
    __syncthreads();
    for (int off = 1; off < 256; off <<= 1) {
        int t = (threadIdx.x >= off) ? s[threadIdx.x - off] : 0;
        __syncthreads();
        s[threadIdx.x] += t;
        __syncthreads();
    }
    if (threadIdx.x < nb) block_sums[threadIdx.x] = s[threadIdx.x] - v;  // exclusive
}

// phase C: per-block exclusive scan + block offset -> row_start
__global__ __launch_bounds__(256) void scan_phaseC(
    const int* __restrict__ counts, const int* __restrict__ block_sums,
    int* __restrict__ row_start, int n, int n_edges)
{
    __shared__ int s[256];
    int i = blockIdx.x * 256 + threadIdx.x;
    int v = (i < n) ? counts[i] : 0;
    s[threadIdx.x] = v;
    __syncthreads();
    for (int off = 1; off < 256; off <<= 1) {
        int t = (threadIdx.x >= off) ? s[threadIdx.x - off] : 0;
        __syncthreads();
        s[threadIdx.x] += t;
        __syncthreads();
    }
    if (i < n) row_start[i] = s[threadIdx.x] - v + block_sums[blockIdx.x];
    if (blockIdx.x == 0 && threadIdx.x == 0) row_start[n] = n_edges;
}

__global__ __launch_bounds__(256) void fill_kernel(
    const int* __restrict__ src, const int* __restrict__ dst,
    int* __restrict__ cursor, int* __restrict__ csr_src, int n_edges)
{
    int e = blockIdx.x * 256 + threadIdx.x;
    if (e >= n_edges) return;
    int pos = atomicAdd(&cursor[dst[e]], 1);
    csr_src[pos] = src[e];
}

// ---------------- gather aggregation (fused x + sum) -----------------------
// One 32-lane group per destination node; lane f handles float4 #f of the
// 128-float row. out[node] = x[node] + sum_{e in-edges} x[src[e]].
__global__ __launch_bounds__(256) void gather_agg_kernel(
    const float4* __restrict__ x4, const int* __restrict__ row_start,
    const int* __restrict__ csr_src, float4* __restrict__ out, int n_nodes)
{
    int t = blockIdx.x * 256 + threadIdx.x;
    int node = t >> 5;
    int lane = t & 31;
    if (node >= n_nodes) return;
    int lo = row_start[node];
    int hi = row_start[node + 1];

    float4 acc = x4[(size_t)node * 32 + lane];  // fused self term
    int e = lo;
    for (; e + 1 < hi; e += 2) {                // 2-edge unroll for MLP of loads
        int s0 = csr_src[e];
        int s1 = csr_src[e + 1];
        float4 v0 = x4[(size_t)s0 * 32 + lane];
        float4 v1 = x4[(size_t)s1 * 32 + lane];
        acc.x += v0.x + v1.x;
        acc.y += v0.y + v1.y;
        acc.z += v0.z + v1.z;
        acc.w += v0.w + v1.w;
    }
    if (e < hi) {
        int s0 = csr_src[e];
        float4 v0 = x4[(size_t)s0 * 32 + lane];
        acc.x += v0.x; acc.y += v0.y; acc.z += v0.z; acc.w += v0.w;
    }
    out[(size_t)node * 32 + lane] = acc;
}

// ---------------- tiled SGEMM (fp32 vector ALU) ----------------------------
// C[M x 128] = relu(A @ W[128 x 128] + bias). 256 thr, 64x128 tile, 8x4/thread.
__global__ __launch_bounds__(256) void gemm128_kernel(
    const float* __restrict__ A1, const float* __restrict__ W,
    const float* __restrict__ bias, float* __restrict__ C, int M)
{
    __shared__ float As[16][68];
    __shared__ float Bs[16][128];

    const int t  = threadIdx.x;
    const int tx = t & 31;
    const int ty = t >> 5;
    const int row0 = blockIdx.x * 64;

    float acc[8][4];
#pragma unroll
    for (int i = 0; i < 8; ++i)
#pragma unroll
        for (int j = 0; j < 4; ++j) acc[i][j] = 0.f;

    const int arow = t >> 2;
    const int kq   = t & 3;
    const int grow = row0 + arow;
    const int kr   = t >> 5;

    for (int k0 = 0; k0 < IN_DIM; k0 += 16) {
        float4 av = make_float4(0.f, 0.f, 0.f, 0.f);
        if (grow < M)
            av = *(const float4*)(A1 + (size_t)grow * IN_DIM + k0 + kq * 4);
        float4 w0 = *(const float4*)(W + (size_t)(k0 + kr)     * IN_DIM + tx * 4);
        float4 w1 = *(const float4*)(W + (size_t)(k0 + kr + 8) * IN_DIM + tx * 4);

        As[kq * 4 + 0][arow] = av.x;
        As[kq * 4 + 1][arow] = av.y;
        As[kq * 4 + 2][arow] = av.z;
        As[kq * 4 + 3][arow] = av.w;
        *(float4*)&Bs[kr][tx * 4]     = w0;
        *(float4*)&Bs[kr + 8][tx * 4] = w1;
        __syncthreads();

#pragma unroll
        for (int kk = 0; kk < 16; ++kk) {
            float4 a0 = *(const float4*)&As[kk][ty * 8];
            float4 a1 = *(const float4*)&As[kk][ty * 8 + 4];
            float4 w  = *(const float4*)&Bs[kk][tx * 4];
            float a[8] = {a0.x, a0.y, a0.z, a0.w, a1.x, a1.y, a1.z, a1.w};
            float wv[4] = {w.x, w.y, w.z, w.w};
#pragma unroll
            for (int i = 0; i < 8; ++i)
#pragma unroll
                for (int j = 0; j < 4; ++j)
                    acc[i][j] = fmaf(a[i], wv[j], acc[i][j]);
        }
        __syncthreads();
    }

    float4 bv = *(const float4*)(bias + tx * 4);
    float b[4] = {bv.x, bv.y, bv.z, bv.w};
#pragma unroll
    for (int i = 0; i < 8; ++i) {
        int r = row0 + ty * 8 + i;
        if (r < M) {
            float4 o;
            o.x = fmaxf(acc[i][0] + b[0], 0.f);
            o.y = fmaxf(acc[i][1] + b[1], 0.f);
            o.z = fmaxf(acc[i][2] + b[2], 0.f);
            o.w = fmaxf(acc[i][3] + b[3], 0.f);
            *(float4*)(C + (size_t)r * IN_DIM + tx * 4) = o;
        }
    }
}

// ---------------- pool + heads ---------------------------------------------

__device__ __forceinline__ int lower_bound_i(const int* __restrict__ a, int n, int v) {
    int lo = 0, hi = n;
    while (lo < hi) {
        int mid = (lo + hi) >> 1;
        if (a[mid] < v) lo = mid + 1; else hi = mid;
    }
    return lo;
}

__global__ __launch_bounds__(128) void pool_kernel(
    const float* __restrict__ h, const int* __restrict__ batch,
    float* __restrict__ pooled, int n_nodes, int n_graphs)
{
    int g = blockIdx.x;
    int lo = lower_bound_i(batch, n_nodes, g);
    int hi = lower_bound_i(batch, n_nodes, g + 1);
    int j = threadIdx.x;
    float acc = 0.f;
    for (int i = lo; i < hi; ++i)
        acc += h[(size_t)i * IN_DIM + j];
    float cnt = (float)(hi - lo);
    pooled[(size_t)g * IN_DIM + j] = acc / fmaxf(cnt, 1.0f);
}

__global__ __launch_bounds__(64) void head_kernel(
    const float* __restrict__ pooled,
    const float* __restrict__ Ws,  const float* __restrict__ bs,
    const float* __restrict__ WlS, const float* __restrict__ blS,
    const float* __restrict__ WlP, const float* __restrict__ blP,
    const float* __restrict__ WnR, const float* __restrict__ bnR,
    float* __restrict__ out, int n_graphs)
{
    int g = blockIdx.x;
    int j = threadIdx.x;
    const float* p = pooled + (size_t)g * IN_DIM;
    float acc = bs[j];
#pragma unroll 8
    for (int k = 0; k < IN_DIM; ++k)
        acc = fmaf(p[k], Ws[k * 64 + j], acc);
    float gj = fmaxf(acc, 0.f);
    float s1 = gj * WlS[j];
    float s2 = gj * WlP[j];
    float s3 = gj * WnR[j];
#pragma unroll
    for (int off = 32; off > 0; off >>= 1) {
        s1 += __shfl_down(s1, off);
        s2 += __shfl_down(s2, off);
        s3 += __shfl_down(s3, off);
    }
    if (j == 0) {
        out[g]                = s1 + blS[0];
        out[n_graphs + g]     = s2 + blP[0];
        out[2 * n_graphs + g] = s3 + bnR[0];
    }
}

// ---------------- launch ---------------------------------------------------

extern "C" void kernel_launch(void* const* d_in, const int* in_sizes, int n_in,
                              void* d_out, int out_size, void* d_ws, size_t ws_size,
                              hipStream_t stream)
{
    const float* x   = (const float*)d_in[0];
    const int*   ei  = (const int*)d_in[1];
    const int*   bat = (const int*)d_in[2];
    const float* W1a = (const float*)d_in[3];
    const float* b1a = (const float*)d_in[4];
    const float* W1b = (const float*)d_in[5];
    const float* b1b = (const float*)d_in[6];
    const float* W2a = (const float*)d_in[7];
    const float* b2a = (const float*)d_in[8];
    const float* W2b = (const float*)d_in[9];
    const float* b2b = (const float*)d_in[10];
    const float* Ws  = (const float*)d_in[11];
    const float* bs  = (const float*)d_in[12];
    const float* WlS = (const float*)d_in[13];
    const float* blS = (const float*)d_in[14];
    const float* WlP = (const float*)d_in[15];
    const float* blP = (const float*)d_in[16];
    const float* WnR = (const float*)d_in[17];
    const float* bnR = (const float*)d_in[18];

    const int n_nodes  = in_sizes[0] / IN_DIM;
    const int n_edges  = in_sizes[1] / 2;
    const int n_graphs = out_size / 3;
    const int* src = ei;
    const int* dst = ei + n_edges;

    const size_t node_elems   = (size_t)n_nodes * IN_DIM;
    const size_t pooled_elems = (size_t)n_graphs * IN_DIM;

    float* h1     = (float*)d_ws;
    float* buf2   = h1   + node_elems;
    float* bufA   = buf2 + node_elems;          // gather output (x + agg)
    float* pooled = bufA + node_elems;
    int* row_start = (int*)(pooled + pooled_elems);   // n_nodes + 1
    int* cursor    = row_start + (n_nodes + 1);       // n_nodes (also histogram)
    int* csr_src   = cursor + n_nodes;                // n_edges

    const int eblocks = (n_edges + 255) / 256;
    const int nblocks256 = (n_nodes + 255) / 256;     // 196 for 50K (<=256: scan ok)
    const int gatherblocks = (int)(((size_t)n_nodes * 32 + 255) / 256);
    const int gemmblocks = (n_nodes + 63) / 64;

    // ---- CSR build (dst-sorted adjacency) ----
    hipMemsetAsync(cursor, 0, (size_t)n_nodes * sizeof(int), stream);
    hist_kernel<<<eblocks, 256, 0, stream>>>(dst, cursor, n_edges);
    scan_phaseA<<<nblocks256, 256, 0, stream>>>(cursor, csr_src /*scratch for block sums*/, n_nodes);
    scan_phaseB<<<1, 256, 0, stream>>>(csr_src, nblocks256);
    scan_phaseC<<<nblocks256, 256, 0, stream>>>(cursor, csr_src, row_start, n_nodes, n_edges);
    hipMemcpyAsync(cursor, row_start, (size_t)n_nodes * sizeof(int),
                   hipMemcpyDeviceToDevice, stream);
    fill_kernel<<<eblocks, 256, 0, stream>>>(src, dst, cursor, csr_src, n_edges);

    // ---- layer 1 ----
    gather_agg_kernel<<<gatherblocks, 256, 0, stream>>>(
        (const float4*)x, row_start, csr_src, (float4*)bufA, n_nodes);
    gemm128_kernel<<<gemmblocks, 256, 0, stream>>>(bufA, W1a, b1a, h1, n_nodes);
    gemm128_kernel<<<gemmblocks, 256, 0, stream>>>(h1,   W1b, b1b, buf2, n_nodes);

    // ---- layer 2 ----
    gather_agg_kernel<<<gatherblocks, 256, 0, stream>>>(
        (const float4*)buf2, row_start, csr_src, (float4*)bufA, n_nodes);
    gemm128_kernel<<<gemmblocks, 256, 0, stream>>>(bufA, W2a, b2a, h1, n_nodes);
    gemm128_kernel<<<gemmblocks, 256, 0, stream>>>(h1,   W2b, b2b, buf2, n_nodes);

    // ---- pool + heads ----
    pool_kernel<<<n_graphs, 128, 0, stream>>>(buf2, bat, pooled, n_nodes, n_graphs);
    head_kernel<<<n_graphs, 64, 0, stream>>>(pooled, Ws, bs, WlS, blS, WlP, blP,
                                             WnR, bnR, (float*)d_out, n_graphs);
}

// Round 3
// 612.361 us; speedup vs baseline: 9.1639x; 1.0918x over previous
//
#include <hip/hip_runtime.h>
#include <hip/hip_bf16.h>

// ---------------------------------------------------------------------------
// GIN multi-task forward on MI355X.
// R3: XCD-partitioned CSR fill (each XCD writes only its ~800KB csr window ->
// L2-resident, kills the 16x partial-line write amplification seen in R2),
// int4-batched histogram, scan writes cursor copy (drops d2d memcpy),
// unrolled gather.
// ---------------------------------------------------------------------------

#define IN_DIM 128
#define NPART 8          // one partition per XCD

// ---------------- CSR build ------------------------------------------------

__global__ __launch_bounds__(256) void hist_kernel(
    const int* __restrict__ dst, int* __restrict__ counts, int n_edges)
{
    int e0 = (blockIdx.x * 256 + threadIdx.x) * 4;
    if (e0 + 3 < n_edges) {
        int4 d = *(const int4*)(dst + e0);
        atomicAdd(&counts[d.x], 1);
        atomicAdd(&counts[d.y], 1);
        atomicAdd(&counts[d.z], 1);
        atomicAdd(&counts[d.w], 1);
    } else {
        for (int e = e0; e < n_edges; ++e) atomicAdd(&counts[dst[e]], 1);
    }
}

// phase A: per-block (256 elems) totals
__global__ __launch_bounds__(256) void scan_phaseA(
    const int* __restrict__ counts, int* __restrict__ block_sums, int n)
{
    __shared__ int s[256];
    int i = blockIdx.x * 256 + threadIdx.x;
    s[threadIdx.x] = (i < n) ? counts[i] : 0;
    __syncthreads();
    for (int off = 128; off > 0; off >>= 1) {
        if (threadIdx.x < off) s[threadIdx.x] += s[threadIdx.x + off];
        __syncthreads();
    }
    if (threadIdx.x == 0) block_sums[blockIdx.x] = s[0];
}

// phase B: single-block exclusive scan of block sums (nb <= 256)
__global__ __launch_bounds__(256) void scan_phaseB(int* __restrict__ block_sums, int nb)
{
    __shared__ int s[256];
    int v = (threadIdx.x < nb) ? block_sums[threadIdx.x] : 0;
    s[threadIdx.x] = v;
    __syncthreads();
    for (int off = 1; off < 256; off <<= 1) {
        int t = (threadIdx.x >= off) ? s[threadIdx.x - off] : 0;
        __syncthreads();
        s[threadIdx.x] += t;
        __syncthreads();
    }
    if (threadIdx.x < nb) block_sums[threadIdx.x] = s[threadIdx.x] - v;  // exclusive
}

// phase C: per-block exclusive scan + block offset -> row_start AND cursor
__global__ __launch_bounds__(256) void scan_phaseC(
    const int* __restrict__ counts, const int* __restrict__ block_sums,
    int* __restrict__ row_start, int* __restrict__ cursor, int n, int n_edges)
{
    __shared__ int s[256];
    int i = blockIdx.x * 256 + threadIdx.x;
    int v = (i < n) ? counts[i] : 0;
    s[threadIdx.x] = v;
    __syncthreads();
    for (int off = 1; off < 256; off <<= 1) {
        int t = (threadIdx.x >= off) ? s[threadIdx.x - off] : 0;
        __syncthreads();
        s[threadIdx.x] += t;
        __syncthreads();
    }
    if (i < n) {
        int rs = s[threadIdx.x] - v + block_sums[blockIdx.x];
        row_start[i] = rs;
        cursor[i] = rs;
    }
    if (blockIdx.x == 0 && threadIdx.x == 0) row_start[n] = n_edges;
}

// XCD-partitioned fill: block b handles partition p = b & 7, edge chunk b >> 3.
// Only edges with dst in partition p's node range are emitted, so each XCD
// writes a contiguous ~1/8 window of csr_src that fits its private L2.
__global__ __launch_bounds__(256) void fill_part_kernel(
    const int* __restrict__ src, const int* __restrict__ dst,
    int* __restrict__ cursor, int* __restrict__ csr_src,
    int n_edges, int n_nodes)
{
    const int p      = blockIdx.x & (NPART - 1);
    const int chunk  = blockIdx.x >> 3;
    const int pstart = (int)(((long long)n_nodes * p)       / NPART);
    const int pend   = (int)(((long long)n_nodes * (p + 1)) / NPART);

    int e0 = chunk * (256 * 4) + threadIdx.x * 4;
    if (e0 >= n_edges) return;
    if (e0 + 3 < n_edges) {
        int4 d = *(const int4*)(dst + e0);
        int4 s = *(const int4*)(src + e0);
        if (d.x >= pstart && d.x < pend) csr_src[atomicAdd(&cursor[d.x], 1)] = s.x;
        if (d.y >= pstart && d.y < pend) csr_src[atomicAdd(&cursor[d.y], 1)] = s.y;
        if (d.z >= pstart && d.z < pend) csr_src[atomicAdd(&cursor[d.z], 1)] = s.z;
        if (d.w >= pstart && d.w < pend) csr_src[atomicAdd(&cursor[d.w], 1)] = s.w;
    } else {
        for (int e = e0; e < n_edges; ++e) {
            int d = dst[e];
            if (d >= pstart && d < pend) csr_src[atomicAdd(&cursor[d], 1)] = src[e];
        }
    }
}

// ---------------- gather aggregation (fused x + sum) -----------------------
// One 32-lane group per destination node; lane f handles float4 #f of the
// 128-float row. out[node] = x[node] + sum_{e in-edges} x[src[e]].
__global__ __launch_bounds__(256) void gather_agg_kernel(
    const float4* __restrict__ x4, const int* __restrict__ row_start,
    const int* __restrict__ csr_src, float4* __restrict__ out, int n_nodes)
{
    int t = blockIdx.x * 256 + threadIdx.x;
    int node = t >> 5;
    int lane = t & 31;
    if (node >= n_nodes) return;
    int lo = row_start[node];
    int hi = row_start[node + 1];

    float4 acc = x4[(size_t)node * 32 + lane];  // fused self term
    int e = lo;
    for (; e + 3 < hi; e += 4) {
        int s0 = csr_src[e];
        int s1 = csr_src[e + 1];
        int s2 = csr_src[e + 2];
        int s3 = csr_src[e + 3];
        float4 v0 = x4[(size_t)s0 * 32 + lane];
        float4 v1 = x4[(size_t)s1 * 32 + lane];
        float4 v2 = x4[(size_t)s2 * 32 + lane];
        float4 v3 = x4[(size_t)s3 * 32 + lane];
        acc.x += (v0.x + v1.x) + (v2.x + v3.x);
        acc.y += (v0.y + v1.y) + (v2.y + v3.y);
        acc.z += (v0.z + v1.z) + (v2.z + v3.z);
        acc.w += (v0.w + v1.w) + (v2.w + v3.w);
    }
    for (; e < hi; ++e) {
        int s0 = csr_src[e];
        float4 v0 = x4[(size_t)s0 * 32 + lane];
        acc.x += v0.x; acc.y += v0.y; acc.z += v0.z; acc.w += v0.w;
    }
    out[(size_t)node * 32 + lane] = acc;
}

// ---------------- tiled SGEMM (fp32 vector ALU) ----------------------------
// C[M x 128] = relu(A @ W[128 x 128] + bias). 256 thr, 64x128 tile, 8x4/thread.
__global__ __launch_bounds__(256) void gemm128_kernel(
    const float* __restrict__ A1, const float* __restrict__ W,
    const float* __restrict__ bias, float* __restrict__ C, int M)
{
    __shared__ float As[16][68];
    __shared__ float Bs[16][128];

    const int t  = threadIdx.x;
    const int tx = t & 31;
    const int ty = t >> 5;
    const int row0 = blockIdx.x * 64;

    float acc[8][4];
#pragma unroll
    for (int i = 0; i < 8; ++i)
#pragma unroll
        for (int j = 0; j < 4; ++j) acc[i][j] = 0.f;

    const int arow = t >> 2;
    const int kq   = t & 3;
    const int grow = row0 + arow;
    const int kr   = t >> 5;

    for (int k0 = 0; k0 < IN_DIM; k0 += 16) {
        float4 av = make_float4(0.f, 0.f, 0.f, 0.f);
        if (grow < M)
            av = *(const float4*)(A1 + (size_t)grow * IN_DIM + k0 + kq * 4);
        float4 w0 = *(const float4*)(W + (size_t)(k0 + kr)     * IN_DIM + tx * 4);
        float4 w1 = *(const float4*)(W + (size_t)(k0 + kr + 8) * IN_DIM + tx * 4);

        As[kq * 4 + 0][arow] = av.x;
        As[kq * 4 + 1][arow] = av.y;
        As[kq * 4 + 2][arow] = av.z;
        As[kq * 4 + 3][arow] = av.w;
        *(float4*)&Bs[kr][tx * 4]     = w0;
        *(float4*)&Bs[kr + 8][tx * 4] = w1;
        __syncthreads();

#pragma unroll
        for (int kk = 0; kk < 16; ++kk) {
            float4 a0 = *(const float4*)&As[kk][ty * 8];
            float4 a1 = *(const float4*)&As[kk][ty * 8 + 4];
            float4 w  = *(const float4*)&Bs[kk][tx * 4];
            float a[8] = {a0.x, a0.y, a0.z, a0.w, a1.x, a1.y, a1.z, a1.w};
            float wv[4] = {w.x, w.y, w.z, w.w};
#pragma unroll
            for (int i = 0; i < 8; ++i)
#pragma unroll
                for (int j = 0; j < 4; ++j)
                    acc[i][j] = fmaf(a[i], wv[j], acc[i][j]);
        }
        __syncthreads();
    }

    float4 bv = *(const float4*)(bias + tx * 4);
    float b[4] = {bv.x, bv.y, bv.z, bv.w};
#pragma unroll
    for (int i = 0; i < 8; ++i) {
        int r = row0 + ty * 8 + i;
        if (r < M) {
            float4 o;
            o.x = fmaxf(acc[i][0] + b[0], 0.f);
            o.y = fmaxf(acc[i][1] + b[1], 0.f);
            o.z = fmaxf(acc[i][2] + b[2], 0.f);
            o.w = fmaxf(acc[i][3] + b[3], 0.f);
            *(float4*)(C + (size_t)r * IN_DIM + tx * 4) = o;
        }
    }
}

// ---------------- pool + heads ---------------------------------------------

__device__ __forceinline__ int lower_bound_i(const int* __restrict__ a, int n, int v) {
    int lo = 0, hi = n;
    while (lo < hi) {
        int mid = (lo + hi) >> 1;
        if (a[mid] < v) lo = mid + 1; else hi = mid;
    }
    return lo;
}

__global__ __launch_bounds__(128) void pool_kernel(
    const float* __restrict__ h, const int* __restrict__ batch,
    float* __restrict__ pooled, int n_nodes, int n_graphs)
{
    int g = blockIdx.x;
    int lo = lower_bound_i(batch, n_nodes, g);
    int hi = lower_bound_i(batch, n_nodes, g + 1);
    int j = threadIdx.x;
    float acc = 0.f;
    for (int i = lo; i < hi; ++i)
        acc += h[(size_t)i * IN_DIM + j];
    float cnt = (float)(hi - lo);
    pooled[(size_t)g * IN_DIM + j] = acc / fmaxf(cnt, 1.0f);
}

__global__ __launch_bounds__(64) void head_kernel(
    const float* __restrict__ pooled,
    const float* __restrict__ Ws,  const float* __restrict__ bs,
    const float* __restrict__ WlS, const float* __restrict__ blS,
    const float* __restrict__ WlP, const float* __restrict__ blP,
    const float* __restrict__ WnR, const float* __restrict__ bnR,
    float* __restrict__ out, int n_graphs)
{
    int g = blockIdx.x;
    int j = threadIdx.x;
    const float* p = pooled + (size_t)g * IN_DIM;
    float acc = bs[j];
#pragma unroll 8
    for (int k = 0; k < IN_DIM; ++k)
        acc = fmaf(p[k], Ws[k * 64 + j], acc);
    float gj = fmaxf(acc, 0.f);
    float s1 = gj * WlS[j];
    float s2 = gj * WlP[j];
    float s3 = gj * WnR[j];
#pragma unroll
    for (int off = 32; off > 0; off >>= 1) {
        s1 += __shfl_down(s1, off);
        s2 += __shfl_down(s2, off);
        s3 += __shfl_down(s3, off);
    }
    if (j == 0) {
        out[g]                = s1 + blS[0];
        out[n_graphs + g]     = s2 + blP[0];
        out[2 * n_graphs + g] = s3 + bnR[0];
    }
}

// ---------------- launch ---------------------------------------------------

extern "C" void kernel_launch(void* const* d_in, const int* in_sizes, int n_in,
                              void* d_out, int out_size, void* d_ws, size_t ws_size,
                              hipStream_t stream)
{
    const float* x   = (const float*)d_in[0];
    const int*   ei  = (const int*)d_in[1];
    const int*   bat = (const int*)d_in[2];
    const float* W1a = (const float*)d_in[3];
    const float* b1a = (const float*)d_in[4];
    const float* W1b = (const float*)d_in[5];
    const float* b1b = (const float*)d_in[6];
    const float* W2a = (const float*)d_in[7];
    const float* b2a = (const float*)d_in[8];
    const float* W2b = (const float*)d_in[9];
    const float* b2b = (const float*)d_in[10];
    const float* Ws  = (const float*)d_in[11];
    const float* bs  = (const float*)d_in[12];
    const float* WlS = (const float*)d_in[13];
    const float* blS = (const float*)d_in[14];
    const float* WlP = (const float*)d_in[15];
    const float* blP = (const float*)d_in[16];
    const float* WnR = (const float*)d_in[17];
    const float* bnR = (const float*)d_in[18];

    const int n_nodes  = in_sizes[0] / IN_DIM;
    const int n_edges  = in_sizes[1] / 2;
    const int n_graphs = out_size / 3;
    const int* src = ei;
    const int* dst = ei + n_edges;

    const size_t node_elems   = (size_t)n_nodes * IN_DIM;
    const size_t pooled_elems = (size_t)n_graphs * IN_DIM;

    float* h1     = (float*)d_ws;
    float* buf2   = h1   + node_elems;
    float* bufA   = buf2 + node_elems;          // gather output (x + agg)
    float* pooled = bufA + node_elems;
    int* row_start = (int*)(pooled + pooled_elems);   // n_nodes + 1
    int* cursor    = row_start + (n_nodes + 1);       // n_nodes (also histogram)
    int* csr_src   = cursor + n_nodes;                // n_edges

    const int eblocks4 = (n_edges + 1023) / 1024;     // 4 edges/thread
    const int nblocks256 = (n_nodes + 255) / 256;     // 196 for 50K (<=256: scan ok)
    const int gatherblocks = (int)(((size_t)n_nodes * 32 + 255) / 256);
    const int gemmblocks = (n_nodes + 63) / 64;
    const int fillblocks = NPART * eblocks4;

    // ---- CSR build (dst-sorted adjacency) ----
    hipMemsetAsync(cursor, 0, (size_t)n_nodes * sizeof(int), stream);
    hist_kernel<<<eblocks4, 256, 0, stream>>>(dst, cursor, n_edges);
    scan_phaseA<<<nblocks256, 256, 0, stream>>>(cursor, csr_src /*scratch*/, n_nodes);
    scan_phaseB<<<1, 256, 0, stream>>>(csr_src, nblocks256);
    scan_phaseC<<<nblocks256, 256, 0, stream>>>(cursor, csr_src, row_start,
                                                cursor, n_nodes, n_edges);
    fill_part_kernel<<<fillblocks, 256, 0, stream>>>(src, dst, cursor, csr_src,
                                                     n_edges, n_nodes);

    // ---- layer 1 ----
    gather_agg_kernel<<<gatherblocks, 256, 0, stream>>>(
        (const float4*)x, row_start, csr_src, (float4*)bufA, n_nodes);
    gemm128_kernel<<<gemmblocks, 256, 0, stream>>>(bufA, W1a, b1a, h1, n_nodes);
    gemm128_kernel<<<gemmblocks, 256, 0, stream>>>(h1,   W1b, b1b, buf2, n_nodes);

    // ---- layer 2 ----
    gather_agg_kernel<<<gatherblocks, 256, 0, stream>>>(
        (const float4*)buf2, row_start, csr_src, (float4*)bufA, n_nodes);
    gemm128_kernel<<<gemmblocks, 256, 0, stream>>>(bufA, W2a, b2a, h1, n_nodes);
    gemm128_kernel<<<gemmblocks, 256, 0, stream>>>(h1,   W2b, b2b, buf2, n_nodes);

    // ---- pool + heads ----
    pool_kernel<<<n_graphs, 128, 0, stream>>>(buf2, bat, pooled, n_nodes, n_graphs);
    head_kernel<<<n_graphs, 64, 0, stream>>>(pooled, Ws, bs, WlS, blS, WlP, blP,
                                             WnR, bnR, (float*)d_out, n_graphs);
}